// Round 5
// baseline (47.108 us; speedup 1.0000x reference)
//
#include <hip/hip_runtime.h>
#include <math.h>

#define B 512
#define M 4096
#define T 48
#define MCHUNK 4
#define NCH (M / MCHUNK)   // 1024 m-chunks

// ws layout (bytes):
//   [0, 4 MiB)            pval[b][ch]: packed (float_bits(dist)<<32 | m), u64
//   [4 MiB, 4 MiB+192KiB) tgtP[q][b]: float4 (t=2q,2q+1 pair), q<24

// ---- Kernel 0: pack target (B,T,2) -> (T/2, B) float4; zero loss slot -----
__global__ __launch_bounds__(256) void k_prep(const float* __restrict__ target,
                                              float4* __restrict__ tgtP,
                                              float* __restrict__ out0) {
    int i = blockIdx.x * 256 + threadIdx.x;        // over B*T/2 = 12288 float4
    if (i == 0) out0[0] = 0.0f;
    int b = i / (T / 2), q = i - b * (T / 2);
    float4 v = *(const float4*)(target + (size_t)b * (T * 2) + 4 * q); // coalesced
    tgtP[q * B + b] = v;                            // 24 write streams, fine
}

// ---- Kernel 1: distance. lane = b; m-chunk staged in LDS (broadcast reads) -
__global__ __launch_bounds__(256, 8) void k_dist(const float4* __restrict__ tgtP,
                                                 const float* __restrict__ memory,
                                                 unsigned long long* __restrict__ pval) {
    const int tid = threadIdx.x;
    const int ch  = blockIdx.x;
    const int b   = blockIdx.y * 256 + tid;
    const int m0  = ch * MCHUNK;

    __shared__ float4 smem[MCHUNK * (T / 2)];      // 96 float4 = 1536 B
    if (tid < MCHUNK * (T / 2))
        smem[tid] = ((const float4*)(memory + (size_t)m0 * (T * 2)))[tid];
    __syncthreads();

    float acc0 = 0.f, acc1 = 0.f, acc2 = 0.f, acc3 = 0.f;

#pragma unroll 6
    for (int q = 0; q < T / 2; ++q) {
        float4 g = tgtP[q * B + b];                // coalesced 16B/lane, L2-resident
        {
            float4 mv = smem[0 * (T / 2) + q];     // uniform -> broadcast
            float dx0 = mv.x - g.x, dy0 = mv.y - g.y;
            float dx1 = mv.z - g.z, dy1 = mv.w - g.w;
            acc0 += __builtin_amdgcn_sqrtf(fmaf(dx0, dx0, dy0 * dy0));
            acc0 += __builtin_amdgcn_sqrtf(fmaf(dx1, dx1, dy1 * dy1));
        }
        {
            float4 mv = smem[1 * (T / 2) + q];
            float dx0 = mv.x - g.x, dy0 = mv.y - g.y;
            float dx1 = mv.z - g.z, dy1 = mv.w - g.w;
            acc1 += __builtin_amdgcn_sqrtf(fmaf(dx0, dx0, dy0 * dy0));
            acc1 += __builtin_amdgcn_sqrtf(fmaf(dx1, dx1, dy1 * dy1));
        }
        {
            float4 mv = smem[2 * (T / 2) + q];
            float dx0 = mv.x - g.x, dy0 = mv.y - g.y;
            float dx1 = mv.z - g.z, dy1 = mv.w - g.w;
            acc2 += __builtin_amdgcn_sqrtf(fmaf(dx0, dx0, dy0 * dy0));
            acc2 += __builtin_amdgcn_sqrtf(fmaf(dx1, dx1, dy1 * dy1));
        }
        {
            float4 mv = smem[3 * (T / 2) + q];
            float dx0 = mv.x - g.x, dy0 = mv.y - g.y;
            float dx1 = mv.z - g.z, dy1 = mv.w - g.w;
            acc3 += __builtin_amdgcn_sqrtf(fmaf(dx0, dx0, dy0 * dy0));
            acc3 += __builtin_amdgcn_sqrtf(fmaf(dx1, dx1, dy1 * dy1));
        }
    }

    // per-lane argmin over the 4 chunk members (ascending m -> lowest idx tie)
    float bestv = acc0; int besti = m0;
    if (acc1 < bestv) { bestv = acc1; besti = m0 + 1; }
    if (acc2 < bestv) { bestv = acc2; besti = m0 + 2; }
    if (acc3 < bestv) { bestv = acc3; besti = m0 + 3; }

    pval[(size_t)b * NCH + ch] =
        ((unsigned long long)__float_as_uint(bestv) << 32) | (unsigned int)besti;
}

// ---- Kernel 2: one WAVE per b: argmin + LSE + NLL + mean (shfl only) ------
__global__ __launch_bounds__(256) void k_post(const float* __restrict__ preds,
                                              const unsigned long long* __restrict__ pval,
                                              float* __restrict__ out) {
    const int lane = threadIdx.x & 63;
    const int wv   = threadIdx.x >> 6;
    const int b    = blockIdx.x * 4 + wv;

    // --- argmin over NCH=1024 chunk minima (u64 min == (dist, idx) lexmin) ---
    unsigned long long best = 0xFFFFFFFFFFFFFFFFULL;
#pragma unroll
    for (int j = 0; j < NCH / 64; ++j) {           // 16, coalesced
        unsigned long long p = pval[(size_t)b * NCH + j * 64 + lane];
        if (p < best) best = p;
    }
#pragma unroll
    for (int s = 32; s > 0; s >>= 1) {
        unsigned long long o = __shfl_down(best, s);
        if (o < best) best = o;
    }
    best = __shfl(best, 0);
    const int idx = (int)(unsigned int)(best & 0xFFFFFFFFULL);

    // --- LSE over preds row (64 floats per lane, coalesced float4) ---
    const float4* row = (const float4*)(preds + (size_t)b * M);  // 1024 float4
    float4 v[16];
    float mx = -INFINITY;
#pragma unroll
    for (int j = 0; j < 16; ++j) {
        v[j] = row[j * 64 + lane];
        mx = fmaxf(mx, fmaxf(fmaxf(v[j].x, v[j].y), fmaxf(v[j].z, v[j].w)));
    }
#pragma unroll
    for (int s = 32; s > 0; s >>= 1) mx = fmaxf(mx, __shfl_down(mx, s));
    mx = __shfl(mx, 0);

    float sum = 0.f;
#pragma unroll
    for (int j = 0; j < 16; ++j)
        sum += expf(v[j].x - mx) + expf(v[j].y - mx) + expf(v[j].z - mx) + expf(v[j].w - mx);
#pragma unroll
    for (int s = 32; s > 0; s >>= 1) sum += __shfl_down(sum, s);

    if (lane == 0) {
        float lse = mx + logf(sum);
        float nll = lse - preds[(size_t)b * M + idx];
        atomicAdd(out, nll * (1.0f / B));          // out[0] zeroed by k_prep
        out[1 + b] = (float)idx;
    }
}

extern "C" void kernel_launch(void* const* d_in, const int* in_sizes, int n_in,
                              void* d_out, int out_size, void* d_ws, size_t ws_size,
                              hipStream_t stream) {
    const float* preds  = (const float*)d_in[0];  // (512, 4096)
    const float* target = (const float*)d_in[1];  // (512, 1, 48, 2)
    const float* memory = (const float*)d_in[2];  // (4096, 48, 2)
    float* out = (float*)d_out;                   // [loss, idx[512]]

    char* ws = (char*)d_ws;
    unsigned long long* pval = (unsigned long long*)ws;          // 512*1024*8 = 4 MiB
    float4* tgtP = (float4*)(ws + (size_t)4 * 1024 * 1024);      // 24*512*16 = 192 KiB

    k_prep<<<(B * T / 2) / 256, 256, 0, stream>>>(target, tgtP, out);
    dim3 g1(NCH, B / 256);                        // 1024 x 2 = 2048 blocks (8/CU)
    k_dist<<<g1, 256, 0, stream>>>(tgtP, memory, pval);
    k_post<<<B / 4, 256, 0, stream>>>(preds, pval, out);
}